// Round 2
// baseline (6618.057 us; speedup 1.0000x reference)
//
#include <hip/hip_runtime.h>
#include <hip/hip_cooperative_groups.h>
#include <cstddef>

namespace cg = cooperative_groups;

#define LANG 50257
#define EDIM 512
#define HDIM 1024
#define ADIM 512
#define SLEN 1024
#define NSTEP 25
#define TEMPF 10.0f
#define SOSIDX 1
#define VOFF (NSTEP * LANG)
#define NBLK 256
#define NTHR 1024

// ws layout (floats)
#define WS_P      0                       // 1024*512
#define WS_W1HT   (WS_P + 512 * 1024)     // [a][j] transposed h-part of W1
#define WS_EMBT   (WS_W1HT + 512 * 1024)  // [a][s] transposed embeddings
#define WS_EVECT  (WS_EMBT + 512 * 1024)  // exp(logits), 50257 (pad 50432)
#define WS_ESC    (WS_EVECT + 50432)      // exp(scores), 1024
#define WS_H      (WS_ESC + 1024)         // h double buffer 2*1024
#define WS_EA     (WS_H + 2048)           // emb_acc double buffer 2*512
#define WS_DEN    (WS_EA + 1024)          // word-softmax denom, 2
#define WS_SDEN   (WS_DEN + 2)            // score-softmax denom, 1
#define WS_HPROJ  (WS_SDEN + 62)          // 512
#define WS_ATTN   (WS_HPROJ + 512)        // 512

__device__ __forceinline__ float wred(float x) {
#pragma unroll
  for (int off = 32; off; off >>= 1) x += __shfl_down(x, off);
  return x;
}

__global__ __launch_bounds__(NTHR, 4) void k_decoder(
    const float* __restrict__ hidden, const float* __restrict__ emb_src,
    const float* __restrict__ emb_T,  const float* __restrict__ W_ih,
    const float* __restrict__ W_hh,   const float* __restrict__ b_ih,
    const float* __restrict__ b_hh,   const float* __restrict__ W1,
    const float* __restrict__ b1,     const float* __restrict__ vvec,
    const float* __restrict__ out_W,  const float* __restrict__ out_b,
    float* __restrict__ out, float* __restrict__ ws) {
  cg::grid_group grid = cg::this_grid();
  __shared__ __align__(16) float smem[2560];
  const int tid = threadIdx.x, bid = blockIdx.x;
  const int wid = tid >> 6, lane = tid & 63;

  float* P     = ws + WS_P;
  float* W1hT  = ws + WS_W1HT;
  float* embT  = ws + WS_EMBT;
  float* evect = ws + WS_EVECT;
  float* esc   = ws + WS_ESC;
  float* hws   = ws + WS_H;
  float* eaws  = ws + WS_EA;
  float* denw  = ws + WS_DEN;
  float* sden  = ws + WS_SDEN;
  float* hproj = ws + WS_HPROJ;
  float* attn  = ws + WS_ATTN;

  // ---------------- precompute: P = emb_src @ W1[:A] + b1 (4 rows/block) ----
  {
    for (int i = tid; i < 4 * ADIM; i += NTHR)
      smem[i] = emb_src[(size_t)bid * 4 * ADIM + i];
    __syncthreads();
    if (tid < ADIM) {
      int a = tid;
      float bb = b1[a];
      float acc0 = bb, acc1 = bb, acc2 = bb, acc3 = bb;
      for (int k = 0; k < ADIM; ++k) {
        float w = W1[(size_t)k * ADIM + a];
        acc0 += smem[k] * w;
        acc1 += smem[512 + k] * w;
        acc2 += smem[1024 + k] * w;
        acc3 += smem[1536 + k] * w;
      }
      P[(size_t)(bid * 4 + 0) * ADIM + a] = acc0;
      P[(size_t)(bid * 4 + 1) * ADIM + a] = acc1;
      P[(size_t)(bid * 4 + 2) * ADIM + a] = acc2;
      P[(size_t)(bid * 4 + 3) * ADIM + a] = acc3;
    }
    // transposes: W1hT[a][j] = W1[(A+j)*A + a]; embT[a][s] = emb_src[s*A + a]
    {
      int i0 = bid * 2048 + tid;
      int i1 = i0 + 1024;
      int a0 = i0 >> 10, j0 = i0 & 1023;
      int a1 = i1 >> 10, j1 = i1 & 1023;
      W1hT[i0] = W1[(size_t)(ADIM + j0) * ADIM + a0];
      W1hT[i1] = W1[(size_t)(ADIM + j1) * ADIM + a1];
      embT[i0] = emb_src[(size_t)j0 * ADIM + a0];
      embT[i1] = emb_src[(size_t)j1 * ADIM + a1];
    }
    if (bid == 0) {
      if (tid < EDIM) eaws[tid] = emb_T[(size_t)SOSIDX * EDIM + tid];
      if (tid < HDIM) hws[tid] = hidden[tid];
      if (tid == 0) denw[0] = 1.0f;
    }
  }
  grid.sync();

  for (int t = 0; t < NSTEP; ++t) {
    const int cur = t & 1, nxt = cur ^ 1;
    float* hold = hws + cur * HDIM;
    float* hnew = hws + nxt * HDIM;
    float* ea   = eaws + cur * EDIM;
    float* eanx = eaws + nxt * EDIM;

    // ---- Phase 1: GRU. 4 j/block, 4 partial-waves per j ------------------
    {
      float inv = 1.0f / denw[cur];
      if (tid < EDIM) smem[tid] = ea[tid] * inv;
      smem[EDIM + tid] = hold[tid];
      if (bid == 0 && tid == 8) sden[0] = 0.0f;  // for this step's phase 3
      __syncthreads();
      int jl = wid & 3, part = wid >> 2;
      int j = bid * 4 + jl;
      float ir = 0.f, iz = 0.f, in_ = 0.f;
#pragma unroll
      for (int k = 0; k < 2; ++k) {
        int e = part * 128 + k * 64 + lane;
        float x = smem[e];
        ir  += W_ih[(size_t)j * EDIM + e] * x;
        iz  += W_ih[(size_t)(j + HDIM) * EDIM + e] * x;
        in_ += W_ih[(size_t)(j + 2 * HDIM) * EDIM + e] * x;
      }
      float hr = 0.f, hz = 0.f, hn = 0.f;
#pragma unroll
      for (int k = 0; k < 4; ++k) {
        int e = part * 256 + k * 64 + lane;
        float x = smem[EDIM + e];
        hr += W_hh[(size_t)j * HDIM + e] * x;
        hz += W_hh[(size_t)(j + HDIM) * HDIM + e] * x;
        hn += W_hh[(size_t)(j + 2 * HDIM) * HDIM + e] * x;
      }
#pragma unroll
      for (int off = 32; off; off >>= 1) {
        ir += __shfl_down(ir, off);  iz += __shfl_down(iz, off);  in_ += __shfl_down(in_, off);
        hr += __shfl_down(hr, off);  hz += __shfl_down(hz, off);  hn += __shfl_down(hn, off);
      }
      if (lane == 0) {
        float* pb = smem + 1536 + (jl * 4 + part) * 6;
        pb[0] = ir; pb[1] = iz; pb[2] = in_; pb[3] = hr; pb[4] = hz; pb[5] = hn;
      }
      __syncthreads();
      if (tid < 4) {
        int jj = bid * 4 + tid;
        float sir = 0.f, siz = 0.f, sin_ = 0.f, shr = 0.f, shz = 0.f, shn = 0.f;
#pragma unroll
        for (int p = 0; p < 4; ++p) {
          float* pb = smem + 1536 + (tid * 4 + p) * 6;
          sir += pb[0]; siz += pb[1]; sin_ += pb[2];
          shr += pb[3]; shz += pb[4]; shn += pb[5];
        }
        float r = 1.f / (1.f + expf(-(sir + b_ih[jj] + shr + b_hh[jj])));
        float z = 1.f / (1.f + expf(-(siz + b_ih[jj + HDIM] + shz + b_hh[jj + HDIM])));
        float n = tanhf(sin_ + b_ih[jj + 2 * HDIM] + r * (shn + b_hh[jj + 2 * HDIM]));
        hnew[jj] = (1.f - z) * n + z * smem[EDIM + jj];
      }
    }
    grid.sync();

    // ---- Phase 2: hproj[a] = W1hT[a,:] . hnew. 2 a/block, 8 parts --------
    {
      int al = wid & 1, part = wid >> 1;
      int a = bid * 2 + al;
      float acc = 0.f;
#pragma unroll
      for (int k = 0; k < 2; ++k) {
        int j = part * 128 + k * 64 + lane;
        acc += W1hT[(size_t)a * HDIM + j] * hnew[j];
      }
      acc = wred(acc);
      if (lane == 0) smem[wid] = acc;
      __syncthreads();
      if (tid < 2) {
        float s = 0.f;
#pragma unroll
        for (int p = 0; p < 8; ++p) s += smem[tid + p * 2];
        hproj[bid * 2 + tid] = s;
      }
    }
    grid.sync();

    // ---- Phase 3: escore[s] = exp(v . tanh(P[s]+hproj)); sum -> sden -----
    {
      int sl = wid & 3, part = wid >> 2;
      int s = bid * 4 + sl;
      float acc = 0.f;
#pragma unroll
      for (int k = 0; k < 2; ++k) {
        int a = part * 128 + k * 64 + lane;
        acc += vvec[a] * tanhf(P[(size_t)s * ADIM + a] + hproj[a]);
      }
      acc = wred(acc);
      if (lane == 0) smem[wid] = acc;
      __syncthreads();
      if (tid < 4) {
        float tot = smem[tid] + smem[tid + 4] + smem[tid + 8] + smem[tid + 12];
        float e = expf(tot);
        esc[bid * 4 + tid] = e;
        atomicAdd(sden, e);
      }
    }
    grid.sync();

    // ---- Phase 5: attn[a] = (embT[a,:] . escore)/sden; emit w; zero next -
    {
      float sdv = sden[0];
      int al = wid & 1, part = wid >> 1;
      int a = bid * 2 + al;
      float acc = 0.f;
#pragma unroll
      for (int k = 0; k < 2; ++k) {
        int s = part * 128 + k * 64 + lane;
        acc += embT[(size_t)a * SLEN + s] * esc[s];
      }
      acc = wred(acc);
      if (lane == 0) smem[wid] = acc;
      __syncthreads();
      if (tid < 2) {
        float s = 0.f;
#pragma unroll
        for (int p = 0; p < 8; ++p) s += smem[tid + p * 2];
        attn[bid * 2 + tid] = s / sdv;
      }
      if (bid < 4 && tid < 256)
        out[VOFF + (size_t)t * SLEN + bid * 256 + tid] = esc[bid * 256 + tid] / sdv;
      if (bid == 4 && tid < EDIM) eanx[tid] = 0.f;
      if (bid == 5 && tid == 0) denw[nxt] = 0.f;
    }
    grid.sync();

    // ---- Phase 6: logits + exp + denom partials --------------------------
    {
      smem[tid] = hnew[tid];
      if (tid < ADIM) smem[HDIM + tid] = attn[tid];
      __syncthreads();
      const float4* sm4 = reinterpret_cast<const float4*>(smem);
      float* vout = out + (size_t)t * LANG;
      float dsum = 0.f;
      int wv = bid * 16 + wid;
      for (int l = wv; l < LANG; l += 4096) {
        const float4* row = reinterpret_cast<const float4*>(out_W + (size_t)l * 1536);
        float acc = 0.f;
#pragma unroll
        for (int k = 0; k < 6; ++k) {
          float4 a4 = row[lane + k * 64];
          float4 b4 = sm4[lane + k * 64];
          acc += a4.x * b4.x + a4.y * b4.y + a4.z * b4.z + a4.w * b4.w;
        }
        acc = wred(acc);
        if (lane == 0) {
          float vv = (acc + out_b[l]) * TEMPF;
          vout[l] = vv;
          if (t + 1 < NSTEP) {
            float ev = expf(vv);
            evect[l] = ev;
            dsum += ev;
          }
        }
      }
      if (lane == 0) smem[1600 + wid] = dsum;   // disjoint from merge region
      __syncthreads();
      if (tid == 0 && t + 1 < NSTEP) {
        float s = 0.f;
#pragma unroll
        for (int p = 0; p < 16; ++p) s += smem[1600 + p];
        atomicAdd(&denw[nxt], s);
      }
    }
    grid.sync();

    // ---- Phase 8: emb_acc_next[e] += sum_l evect[l] * emb_T[l,e] ---------
    if (t + 1 < NSTEP) {
      int base = bid * 197;
      int cnt = LANG - base; if (cnt > 197) cnt = 197;
      if (tid < cnt) smem[tid] = evect[base + tid];
      __syncthreads();
      int g = tid >> 8, tl = tid & 255;
      float a0 = 0.f, a1 = 0.f;
      for (int r = g; r < cnt; r += 4) {
        float p = smem[r];
        float2 vv = reinterpret_cast<const float2*>(emb_T + (size_t)(base + r) * EDIM)[tl];
        a0 += p * vv.x; a1 += p * vv.y;
      }
      float* gb = smem + 256 + g * 512;
      gb[2 * tl] = a0; gb[2 * tl + 1] = a1;
      __syncthreads();
      if (tid < EDIM) {
        float s = smem[256 + tid] + smem[256 + 512 + tid] +
                  smem[256 + 1024 + tid] + smem[256 + 1536 + tid];
        atomicAdd(&eanx[tid], s);
      }
    }
    grid.sync();
  }
}

extern "C" void kernel_launch(void* const* d_in, const int* in_sizes, int n_in,
                              void* d_out, int out_size, void* d_ws, size_t ws_size,
                              hipStream_t stream) {
  const float* hidden  = (const float*)d_in[0];
  const float* emb_src = (const float*)d_in[1];
  const float* emb_T   = (const float*)d_in[2];
  const float* W_ih    = (const float*)d_in[3];
  const float* W_hh    = (const float*)d_in[4];
  const float* b_ih    = (const float*)d_in[5];
  const float* b_hh    = (const float*)d_in[6];
  const float* attn_W1 = (const float*)d_in[7];
  const float* attn_b1 = (const float*)d_in[8];
  const float* attn_v  = (const float*)d_in[9];
  const float* out_W   = (const float*)d_in[10];
  const float* out_b   = (const float*)d_in[11];
  float* out = (float*)d_out;
  float* ws  = (float*)d_ws;

  void* args[] = {
    (void*)&hidden, (void*)&emb_src, (void*)&emb_T, (void*)&W_ih, (void*)&W_hh,
    (void*)&b_ih, (void*)&b_hh, (void*)&attn_W1, (void*)&attn_b1, (void*)&attn_v,
    (void*)&out_W, (void*)&out_b, (void*)&out, (void*)&ws
  };
  hipLaunchCooperativeKernel((void*)k_decoder, dim3(NBLK), dim3(NTHR), args, 0, stream);
}

// Round 3
// 3715.847 us; speedup vs baseline: 1.7810x; 1.7810x over previous
//
#include <hip/hip_runtime.h>
#include <cstddef>
#include <cstdint>

#define LANG 50257
#define EDIM 512
#define HDIM 1024
#define ADIM 512
#define SLEN 1024
#define NSTEP 25
#define TEMPF 10.0f
#define SOSIDX 1
#define VOFF (NSTEP * LANG)
#define NBLK 256
#define NTHR 1024
#define NGRP 16
#define GSZ  (NBLK / NGRP)

// ---- ws byte offsets --------------------------------------------------------
#define OFF_OUTWB  0u                    // bf16 out_W  50257*1536*2
#define OFF_EMBTB  154389504u            // bf16 emb_T  50257*512*2
#define OFF_P      205852672u            // fp32 P[s][a] 1024*512
#define OFF_EMBT   207949824u            // fp32 embT[a][s] 512*1024
#define OFF_ESC    210046976u            // 1024
#define OFF_H      210051072u            // 2*1024
#define OFF_HPROJ8 210059264u            // 8*512
#define OFF_EANX8  210075648u            // 8*512
#define OFF_DENWP  210092032u            // 256
#define OFF_SDENP  210093056u            // 256
#define OFF_ATTN   210094080u            // 512
#define OFF_BAR    210096128u            // counters (memset each launch)

__device__ __forceinline__ float wred(float x) {
#pragma unroll
  for (int off = 32; off; off >>= 1) x += __shfl_down(x, off);
  return x;
}

__device__ __forceinline__ unsigned short f2bf(float x) {
  unsigned u = __float_as_uint(x);
  u = u + 0x7FFFu + ((u >> 16) & 1u);   // RNE
  return (unsigned short)(u >> 16);
}

// tree barrier: 16 group counters (64B apart) + root + gen. Monotonic; reset by memset.
__device__ __forceinline__ void gridbar(unsigned* bar, int bid, unsigned round) {
  __syncthreads();
  if (threadIdx.x == 0) {
    __threadfence();
    int g = bid & (NGRP - 1);
    unsigned t = __hip_atomic_fetch_add(&bar[g * 16], 1u, __ATOMIC_RELAXED, __HIP_MEMORY_SCOPE_AGENT);
    if ((t % GSZ) == GSZ - 1) {
      unsigned r = __hip_atomic_fetch_add(&bar[NGRP * 16], 1u, __ATOMIC_RELAXED, __HIP_MEMORY_SCOPE_AGENT);
      if ((r % NGRP) == NGRP - 1) {
        __threadfence();
        __hip_atomic_store(&bar[NGRP * 16 + 16], round, __ATOMIC_RELEASE, __HIP_MEMORY_SCOPE_AGENT);
      }
    }
    while (__hip_atomic_load(&bar[NGRP * 16 + 16], __ATOMIC_ACQUIRE, __HIP_MEMORY_SCOPE_AGENT) < round)
      __builtin_amdgcn_s_sleep(1);
    __threadfence();
  }
  __syncthreads();
}

__global__ __launch_bounds__(NTHR, 4) void k_decoder(
    const float* __restrict__ hidden, const float* __restrict__ emb_src,
    const float* __restrict__ emb_T,  const float* __restrict__ W_ih,
    const float* __restrict__ W_hh,   const float* __restrict__ b_ih,
    const float* __restrict__ b_hh,   const float* __restrict__ W1,
    const float* __restrict__ b1,     const float* __restrict__ vvec,
    const float* __restrict__ out_W,  const float* __restrict__ out_b,
    float* __restrict__ out, char* __restrict__ wsb) {
  __shared__ __align__(16) float smem[9744];
  const int tid = threadIdx.x, bid = blockIdx.x;
  const int wid = tid >> 6, lane = tid & 63;

  float* P      = (float*)(wsb + OFF_P);
  float* embT   = (float*)(wsb + OFF_EMBT);
  float* esc    = (float*)(wsb + OFF_ESC);
  float* hws    = (float*)(wsb + OFF_H);
  float* hproj8 = (float*)(wsb + OFF_HPROJ8);
  float* eanx8  = (float*)(wsb + OFF_EANX8);
  float* denwp  = (float*)(wsb + OFF_DENWP);
  float* sdenp  = (float*)(wsb + OFF_SDENP);
  float* attn   = (float*)(wsb + OFF_ATTN);
  unsigned* bar = (unsigned*)(wsb + OFF_BAR);
  const uint4* oW4 = (const uint4*)(wsb + OFF_OUTWB);
  const uint4* eT4 = (const uint4*)(wsb + OFF_EMBTB);
  unsigned rnd = 0;

  // ================= pre-phase: conversions, P, embT, inits =================
  {
    // out_W -> bf16 (77,194,752 elems = 19,298,688 float4)
    uint2* dst = (uint2*)(wsb + OFF_OUTWB);
    const float4* src = (const float4*)out_W;
    for (int i = bid * NTHR + tid; i < 19298688; i += NBLK * NTHR) {
      float4 f = src[i];
      dst[i] = make_uint2((unsigned)f2bf(f.x) | ((unsigned)f2bf(f.y) << 16),
                          (unsigned)f2bf(f.z) | ((unsigned)f2bf(f.w) << 16));
    }
    // emb_T -> bf16 (25,731,584 elems = 6,432,896 float4)
    uint2* dst2 = (uint2*)(wsb + OFF_EMBTB);
    const float4* src2 = (const float4*)emb_T;
    for (int i = bid * NTHR + tid; i < 6432896; i += NBLK * NTHR) {
      float4 f = src2[i];
      dst2[i] = make_uint2((unsigned)f2bf(f.x) | ((unsigned)f2bf(f.y) << 16),
                           (unsigned)f2bf(f.z) | ((unsigned)f2bf(f.w) << 16));
    }
    // P = emb_src @ W1[:A] + b1  (4 src rows per block)
    for (int i = tid; i < 4 * ADIM; i += NTHR)
      smem[i] = emb_src[(size_t)bid * 4 * ADIM + i];
    __syncthreads();
    if (tid < ADIM) {
      int a = tid;
      float bb = b1[a];
      float a0 = bb, a1 = bb, a2 = bb, a3 = bb;
      for (int k = 0; k < ADIM; ++k) {
        float w = W1[(size_t)k * ADIM + a];
        a0 += smem[k] * w; a1 += smem[512 + k] * w;
        a2 += smem[1024 + k] * w; a3 += smem[1536 + k] * w;
      }
      P[(size_t)(bid * 4 + 0) * ADIM + a] = a0;
      P[(size_t)(bid * 4 + 1) * ADIM + a] = a1;
      P[(size_t)(bid * 4 + 2) * ADIM + a] = a2;
      P[(size_t)(bid * 4 + 3) * ADIM + a] = a3;
    }
    // embT[a][s] = emb_src[s*A + a]
    {
      int i0 = bid * 2048 + tid, i1 = i0 + 1024;
      embT[i0] = emb_src[(size_t)(i0 & 1023) * ADIM + (i0 >> 10)];
      embT[i1] = emb_src[(size_t)(i1 & 1023) * ADIM + (i1 >> 10)];
    }
    if (bid == 0) {
      for (int i = tid; i < 8 * EDIM; i += NTHR)
        eanx8[i] = (i < EDIM) ? emb_T[(size_t)SOSIDX * EDIM + i] : 0.f;
      if (tid < 256) denwp[tid] = (tid == 0) ? 1.0f : 0.0f;
    }
    if (bid == 1) { for (int i = tid; i < 8 * ADIM; i += NTHR) hproj8[i] = 0.f; }
    if (bid == 2) { hws[tid] = hidden[tid]; }
  }
  rnd++; gridbar(bar, bid, rnd);

  for (int t = 0; t < NSTEP; ++t) {
    const int cur = t & 1, nxt = cur ^ 1;
    float* hold = hws + cur * HDIM;
    float* hnew = hws + nxt * HDIM;

    // ==== P1: GRU (+ hproj outer-product scatter) ===========================
    {
      float easum = 0.f;
      if (tid < EDIM) {
#pragma unroll
        for (int k = 0; k < 8; ++k) easum += eanx8[k * EDIM + tid];
      }
      float dp = 0.f;
      if (tid >= 512 && tid < 768) dp = denwp[tid - 512];
      smem[512 + tid] = hold[tid];
      dp = wred(dp);
      if (tid >= 512 && tid < 768 && lane == 0) smem[1632 + (wid - 8)] = dp;
      __syncthreads();
      float inv = 1.0f / (smem[1632] + smem[1633] + smem[1634] + smem[1635]);
      if (tid < EDIM) smem[tid] = easum * inv;
      __syncthreads();

      int jl = wid & 3, part = wid >> 2;
      int j = bid * 4 + jl;
      float ir = 0.f, iz = 0.f, in_ = 0.f;
#pragma unroll
      for (int k = 0; k < 2; ++k) {
        int e = part * 128 + k * 64 + lane;
        float x = smem[e];
        ir  += W_ih[(size_t)j * EDIM + e] * x;
        iz  += W_ih[(size_t)(j + HDIM) * EDIM + e] * x;
        in_ += W_ih[(size_t)(j + 2 * HDIM) * EDIM + e] * x;
      }
      float hr = 0.f, hz = 0.f, hn = 0.f;
#pragma unroll
      for (int k = 0; k < 4; ++k) {
        int e = part * 256 + k * 64 + lane;
        float x = smem[512 + e];
        hr += W_hh[(size_t)j * HDIM + e] * x;
        hz += W_hh[(size_t)(j + HDIM) * HDIM + e] * x;
        hn += W_hh[(size_t)(j + 2 * HDIM) * HDIM + e] * x;
      }
#pragma unroll
      for (int off = 32; off; off >>= 1) {
        ir += __shfl_down(ir, off);  iz += __shfl_down(iz, off);  in_ += __shfl_down(in_, off);
        hr += __shfl_down(hr, off);  hz += __shfl_down(hz, off);  hn += __shfl_down(hn, off);
      }
      if (lane == 0) {
        float* pb = smem + 1536 + (jl * 4 + part) * 6;
        pb[0] = ir; pb[1] = iz; pb[2] = in_; pb[3] = hr; pb[4] = hz; pb[5] = hn;
      }
      __syncthreads();
      if (tid < 4) {
        int jj = bid * 4 + tid;
        float sir = 0.f, siz = 0.f, sin_ = 0.f, shr = 0.f, shz = 0.f, shn = 0.f;
#pragma unroll
        for (int p = 0; p < 4; ++p) {
          float* pb = smem + 1536 + (tid * 4 + p) * 6;
          sir += pb[0]; siz += pb[1]; sin_ += pb[2];
          shr += pb[3]; shz += pb[4]; shn += pb[5];
        }
        float r = 1.f / (1.f + expf(-(sir + b_ih[jj] + shr + b_hh[jj])));
        float z = 1.f / (1.f + expf(-(siz + b_ih[jj + HDIM] + shz + b_hh[jj + HDIM])));
        float n = tanhf(sin_ + b_ih[jj + 2 * HDIM] + r * (shn + b_hh[jj + 2 * HDIM]));
        float hv = (1.f - z) * n + z * smem[512 + jj];
        hnew[jj] = hv;
        smem[1640 + tid] = hv;
      }
      __syncthreads();
      if (tid < ADIM) {
        float s = 0.f;
#pragma unroll
        for (int jl2 = 0; jl2 < 4; ++jl2)
          s += smem[1640 + jl2] * W1[(size_t)(ADIM + bid * 4 + jl2) * ADIM + tid];
        atomicAdd(&hproj8[(bid & 7) * ADIM + tid], s);
      }
    }
    rnd++; gridbar(bar, bid, rnd);

    // ==== P2: scores (reduce hproj8; esc = exp(v.tanh(P+hp)); sdenp) ========
    {
      float hp = 0.f;
      if (tid < ADIM) {
#pragma unroll
        for (int k = 0; k < 8; ++k) hp += hproj8[k * ADIM + tid];
      }
      if (tid >= 512) smem[tid] = vvec[tid - 512];
      if (tid < ADIM) smem[tid] = hp;
      if (bid < 8 && tid < EDIM) eanx8[bid * EDIM + tid] = 0.f;  // for this step's P4
      __syncthreads();
      int sl = wid & 3, part = wid >> 2;
      int s = bid * 4 + sl;
      float acc = 0.f;
#pragma unroll
      for (int k = 0; k < 2; ++k) {
        int a = part * 128 + k * 64 + lane;
        acc += smem[512 + a] * tanhf(P[(size_t)s * ADIM + a] + smem[a]);
      }
      acc = wred(acc);
      if (lane == 0) smem[1024 + wid] = acc;
      __syncthreads();
      if (tid < 4) {
        float tot = smem[1024 + tid] + smem[1028 + tid] + smem[1032 + tid] + smem[1036 + tid];
        float e = expf(tot);
        esc[bid * 4 + tid] = e;
        smem[1040 + tid] = e;
      }
      __syncthreads();
      if (tid == 0)
        sdenp[bid] = smem[1040] + smem[1041] + smem[1042] + smem[1043];
    }
    rnd++; gridbar(bar, bid, rnd);

    // ==== P3: attn + w output + zero hproj8 =================================
    {
      float sp = 0.f;
      if (tid >= 512 && tid < 768) sp = sdenp[tid - 512];
      sp = wred(sp);
      if (tid >= 512 && tid < 768 && lane == 0) smem[16 + (wid - 8)] = sp;
      int al = wid & 1, part = wid >> 1;
      int a = bid * 2 + al;
      float acc = 0.f;
#pragma unroll
      for (int k = 0; k < 2; ++k) {
        int s = part * 128 + k * 64 + lane;
        acc += embT[(size_t)a * SLEN + s] * esc[s];
      }
      acc = wred(acc);
      if (lane == 0) smem[32 + wid] = acc;
      __syncthreads();
      float sden_t = smem[16] + smem[17] + smem[18] + smem[19];
      if (tid < 2) {
        float s = 0.f;
#pragma unroll
        for (int p = 0; p < 8; ++p) s += smem[32 + tid + p * 2];
        attn[bid * 2 + tid] = s / sden_t;
      }
      if (bid < 4 && tid < 256)
        out[VOFF + (size_t)t * SLEN + bid * 256 + tid] = esc[bid * 256 + tid] / sden_t;
      if (bid < 8 && tid < ADIM) hproj8[bid * ADIM + tid] = 0.f;
    }
    rnd++; gridbar(bar, bid, rnd);

    // ==== P4: logits (bf16) + word softmax + embedding feedback =============
    {
      smem[tid] = hnew[tid];
      if (tid < ADIM) smem[HDIM + tid] = attn[tid];
      __syncthreads();
      const float4* sm4 = (const float4*)smem;
      float* vout = out + (size_t)t * LANG;
      const bool fb = (t + 1 < NSTEP);
      float dsum = 0.f;
      float ae[8] = {0.f, 0.f, 0.f, 0.f, 0.f, 0.f, 0.f, 0.f};
      int wv = bid * 16 + wid;
      for (int l = wv; l < LANG; l += 4096) {
        const uint4* rw = oW4 + (size_t)l * 192;
        float acc = 0.f;
#pragma unroll
        for (int k = 0; k < 3; ++k) {
          uint4 u = rw[k * 64 + lane];
          float4 b0 = sm4[k * 128 + lane * 2];
          float4 b1 = sm4[k * 128 + lane * 2 + 1];
          acc += __uint_as_float(u.x << 16) * b0.x + __uint_as_float(u.x & 0xFFFF0000u) * b0.y;
          acc += __uint_as_float(u.y << 16) * b0.z + __uint_as_float(u.y & 0xFFFF0000u) * b0.w;
          acc += __uint_as_float(u.z << 16) * b1.x + __uint_as_float(u.z & 0xFFFF0000u) * b1.y;
          acc += __uint_as_float(u.w << 16) * b1.z + __uint_as_float(u.w & 0xFFFF0000u) * b1.w;
        }
        acc = wred(acc);
        float bc = __shfl(acc, 0);
        float vv = (bc + out_b[l]) * TEMPF;
        if (lane == 0) vout[l] = vv;
        if (fb) {
          float ev = expf(vv);
          dsum += ev;                       // identical on all lanes
          uint4 u = eT4[(size_t)l * 64 + lane];
          ae[0] += ev * __uint_as_float(u.x << 16);
          ae[1] += ev * __uint_as_float(u.x & 0xFFFF0000u);
          ae[2] += ev * __uint_as_float(u.y << 16);
          ae[3] += ev * __uint_as_float(u.y & 0xFFFF0000u);
          ae[4] += ev * __uint_as_float(u.z << 16);
          ae[5] += ev * __uint_as_float(u.z & 0xFFFF0000u);
          ae[6] += ev * __uint_as_float(u.w << 16);
          ae[7] += ev * __uint_as_float(u.w & 0xFFFF0000u);
        }
      }
      if (lane == 0) smem[9728 + wid] = dsum;
      __syncthreads();
      if (fb) {
        if (tid == 0) {
          float tot = 0.f;
#pragma unroll
          for (int p = 0; p < 16; ++p) tot += smem[9728 + p];
          denwp[bid] = tot;
        }
        float* big = smem + 1536;
#pragma unroll
        for (int i = 0; i < 8; ++i) big[wid * 512 + lane * 8 + i] = ae[i];
        __syncthreads();
#pragma unroll
        for (int st = 8; st; st >>= 1) {
          for (int i = tid; i < st * 512; i += NTHR) big[i] += big[i + st * 512];
          __syncthreads();
        }
        if (tid < EDIM) atomicAdd(&eanx8[(bid & 7) * EDIM + tid], big[tid]);
      }
    }
    rnd++; gridbar(bar, bid, rnd);
  }
}

extern "C" void kernel_launch(void* const* d_in, const int* in_sizes, int n_in,
                              void* d_out, int out_size, void* d_ws, size_t ws_size,
                              hipStream_t stream) {
  const float* hidden  = (const float*)d_in[0];
  const float* emb_src = (const float*)d_in[1];
  const float* emb_T   = (const float*)d_in[2];
  const float* W_ih    = (const float*)d_in[3];
  const float* W_hh    = (const float*)d_in[4];
  const float* b_ih    = (const float*)d_in[5];
  const float* b_hh    = (const float*)d_in[6];
  const float* attn_W1 = (const float*)d_in[7];
  const float* attn_b1 = (const float*)d_in[8];
  const float* attn_v  = (const float*)d_in[9];
  const float* out_W   = (const float*)d_in[10];
  const float* out_b   = (const float*)d_in[11];
  float* out = (float*)d_out;
  char* wsb  = (char*)d_ws;

  hipMemsetAsync(wsb + OFF_BAR, 0, 2048, stream);   // barrier counters

  void* args[] = {
    (void*)&hidden, (void*)&emb_src, (void*)&emb_T, (void*)&W_ih, (void*)&W_hh,
    (void*)&b_ih, (void*)&b_hh, (void*)&attn_W1, (void*)&attn_b1, (void*)&attn_v,
    (void*)&out_W, (void*)&out_b, (void*)&out, (void*)&wsb
  };
  hipLaunchCooperativeKernel((void*)k_decoder, dim3(NBLK), dim3(NTHR), args, 0, stream);
}